// Round 16
// baseline (192.462 us; speedup 1.0000x reference)
//
#include <hip/hip_runtime.h>
#include <hip/hip_bf16.h>
#include <math.h>

constexpr int B_ = 8;
constexpr int C_ = 256;
constexpr int N_ = 2048;
constexpr int CN_ = C_ * N_;        // 524288
constexpr int TOT_ = B_ * C_ * N_;  // 4194304
constexpr int BN_ = B_ * N_;        // 16384
constexpr int NT2 = 8;              // 256-wide strips
constexpr int NP2 = 36;             // triangular tiles per batch
constexpr float EPSC = 256.0f * 1e-6f;

typedef __attribute__((ext_vector_type(8))) short bf16x8;
typedef __attribute__((ext_vector_type(4))) float f32x4;
typedef __attribute__((ext_vector_type(2))) unsigned int u32x2;

__device__ __forceinline__ void g2l16(const void* g, void* l) {
    __builtin_amdgcn_global_load_lds(
        (const __attribute__((address_space(1))) void*)g,
        (__attribute__((address_space(3))) void*)l, 16, 0, 0);
}

__device__ __forceinline__ unsigned short bits(__hip_bfloat16 h) {
    union { __hip_bfloat16 b; unsigned short u; } cv;
    cv.b = h;
    return cv.u;
}

__device__ __forceinline__ float b2f(short s) {
    union { float f; unsigned u; } cv;
    cv.u = ((unsigned)(unsigned short)s) << 16;
    return cv.f;
}

// sortable packed key: (monotone float bits << 32) | (2047 - m)  [lower m wins ties]
__device__ __forceinline__ unsigned long long packkey(float v, int m) {
    const unsigned b = __float_as_uint(v);
    const unsigned u = (b & 0x80000000u) ? ~b : (b | 0x80000000u);
    return ((unsigned long long)u << 32) | (unsigned)(2047 - m);
}

__device__ __forceinline__ unsigned packpair(float a, float b) {
    return ((unsigned)bits(__float2bfloat16(b)) << 16) | bits(__float2bfloat16(a));
}

// norm gather helper: sum the 4 ctile slabs
__device__ __forceinline__ float rnormsum(const float* __restrict__ normp, int idx) {
    return 1.0f / sqrtf(normp[idx] + normp[BN_ + idx] + normp[2 * BN_ + idx] +
                        normp[3 * BN_ + idx] + EPSC);
}

// ----------------------------------------- convert (+ norms) ---------------
// grid = 1024 blocks (batch = blk&7), 256 threads. 64c x 64n tile.
// float4 global loads; one barrier; norms via 16-lane shfl_xor.
__global__ __launch_bounds__(256) void convert_kernel(const float* __restrict__ x,
                                                      __hip_bfloat16* __restrict__ hiT,
                                                      __hip_bfloat16* __restrict__ loT,
                                                      float* __restrict__ normp,
                                                      int* __restrict__ rcnt) {
    const int blk = blockIdx.x;
    const int batch = blk & 7;
    const int nt = (blk >> 3) & 31;
    const int ctile = blk >> 8;
    const int n0 = nt << 6, c0 = ctile << 6;
    const int t = threadIdx.x;

    if (blk == 0 && t == 0) rcnt[0] = 0;

    __shared__ float tb[64][65];

    const int i4 = t & 15;
    const int j = t >> 4;
    const float* xp = x + (size_t)batch * CN_ + (size_t)c0 * N_ + n0;
#pragma unroll
    for (int p = 0; p < 4; ++p) {
        const int cl = j + p * 16;
        const float4 v = *(const float4*)(xp + (size_t)cl * N_ + 4 * i4);
        tb[cl][4 * i4 + 0] = v.x;
        tb[cl][4 * i4 + 1] = v.y;
        tb[cl][4 * i4 + 2] = v.z;
        tb[cl][4 * i4 + 3] = v.w;
    }
    __syncthreads();

    const int cq = t & 15;
    const int nb = t >> 4;
    const int c = cq << 2;
#pragma unroll
    for (int r = 0; r < 4; ++r) {
        const int n = nb + r * 16;
        const float v0 = tb[c][n], v1 = tb[c + 1][n];
        const float v2 = tb[c + 2][n], v3 = tb[c + 3][n];
        const __hip_bfloat16 h0 = __float2bfloat16(v0);
        const __hip_bfloat16 h1 = __float2bfloat16(v1);
        const __hip_bfloat16 h2 = __float2bfloat16(v2);
        const __hip_bfloat16 h3 = __float2bfloat16(v3);
        const float g0 = v0 - __bfloat162float(h0);
        const float g1 = v1 - __bfloat162float(h1);
        const float g2 = v2 - __bfloat162float(h2);
        const float g3 = v3 - __bfloat162float(h3);
        const size_t o = ((size_t)batch * N_ + n0 + n) * C_ + c0 + c;
        u32x2 hp, lp;
        hp[0] = ((unsigned)bits(h1) << 16) | bits(h0);
        hp[1] = ((unsigned)bits(h3) << 16) | bits(h2);
        lp[0] = packpair(g0, g1);
        lp[1] = packpair(g2, g3);
        ((u32x2*)hiT)[o >> 2] = hp;
        ((u32x2*)loT)[o >> 2] = lp;
        float nrm = v0 * v0 + v1 * v1 + v2 * v2 + v3 * v3;
#pragma unroll
        for (int d = 1; d < 16; d <<= 1) nrm += __shfl_xor(nrm, d, 64);
        if (cq == 0) normp[ctile * BN_ + batch * N_ + n0 + n] = nrm;
    }
}

// ------------------------------- gram (MFMA, triangular) + argmax ----------
// v256: 256x256 tile per block (was 128x128). grid = 8 x 36 = 288 blocks of
// 512 threads -> ~1.1 occupancy rounds (was 2.125) -- kills the dispatch
// quantization tail that was ~half of gram's 67us. 96 MFMA per barrier (4x
// amortization of the serialization proven irreducible per-step r1-r3); L2
// staged traffic halves (4x in-block reuse). Single 64KB LDS buffer (2-barrier
// per kt). Wave grid 2x4: wave owns 128x64 (acc[8][4] = 128 AGPR; ~200 regs
// -> 1 block/CU; r5 showed the wave-count axis is worth only ~2us).
__global__ __launch_bounds__(512) void gram_mfma_kernel(
        const __hip_bfloat16* __restrict__ hiT, const __hip_bfloat16* __restrict__ loT,
        const float* __restrict__ normp,
        float* __restrict__ pval, int* __restrict__ pidx, float* __restrict__ pval2) {
    const int blk = blockIdx.x;
    const int batch = blk & 7;
    int p = blk >> 3;  // 0..35
    int bn = 0;
    while (p >= NT2 - bn) { p -= NT2 - bn; ++bn; }
    const int bm = bn + p;
    const bool diag = (bn == bm);
    const int n0 = bn << 8, m0 = bm << 8;

    __shared__ short As[256 * 64];  // 32KB
    __shared__ short Bs[256 * 64];  // 32KB
    // epilogue overlay on As (used only after the post-K-loop barrier)
    short* ov = &As[0];
    float (*rv1)[4] = (float(*)[4])(ov + 0);     // 256x4 f32 (4KB)
    int (*ri1)[4] = (int(*)[4])(ov + 2048);
    float (*rv2)[4] = (float(*)[4])(ov + 4096);
    float (*cv1)[2] = (float(*)[2])(ov + 6144);  // 256x2 f32 (2KB)
    int (*ci1)[2] = (int(*)[2])(ov + 7168);
    float (*cv2)[2] = (float(*)[2])(ov + 8192);
    float* rnA = (float*)(ov + 9216);            // 256 f32

    const int tid = threadIdx.x;
    const int l = tid & 63, w = tid >> 6;
    const int lm = l & 15, q = l >> 4;
    const int x7 = lm & 7;
    const int wn = (w >> 2) << 7;  // 0 / 128
    const int wm = (w & 3) << 6;   // 0 / 64 / 128 / 192

    // ---- hoisted stage addresses: 4 slots per thread per array ----
    const size_t bbase = (size_t)batch * CN_;
    const short* gA[4];
    const short* gB[4];
    int ldsoff[4];
#pragma unroll
    for (int pp = 0; pp < 4; ++pp) {
        const int slot = tid + pp * 512;  // 0..2047
        const int r = slot >> 3, sidx = slot & 7;
        const int sw = sidx ^ (r & 7);    // XOR swizzle (self-inverse)
        const short* base = (const short*)((sw < 4) ? hiT : loT);
        gA[pp] = base + bbase + (size_t)(n0 + r) * C_ + (sw & 3) * 8;
        gB[pp] = base + bbase + (size_t)(m0 + r) * C_ + (sw & 3) * 8;
        ldsoff[pp] = slot * 8;
    }
    // ---- hoisted ds_read offsets ----
    int aoffh[8], aoffl[8], boffh[4], boffl[4];
#pragma unroll
    for (int rt = 0; rt < 8; ++rt) {
        const int ra = wn + rt * 16 + lm;
        aoffh[rt] = ra * 64 + ((q ^ x7) * 8);
        aoffl[rt] = ra * 64 + (((4 | q) ^ x7) * 8);
    }
#pragma unroll
    for (int ct = 0; ct < 4; ++ct) {
        const int rb = wm + ct * 16 + lm;
        boffh[ct] = rb * 64 + ((q ^ x7) * 8);
        boffl[ct] = rb * 64 + (((4 | q) ^ x7) * 8);
    }

    f32x4 acc[8][4];
#pragma unroll
    for (int rt = 0; rt < 8; ++rt)
#pragma unroll
        for (int ct = 0; ct < 4; ++ct) acc[rt][ct] = (f32x4){0.f, 0.f, 0.f, 0.f};

    for (int kt = 0; kt < 8; ++kt) {
        __syncthreads();  // previous tile's LDS reads done
#pragma unroll
        for (int pp = 0; pp < 4; ++pp) {
            g2l16(gA[pp] + kt * 32, As + ldsoff[pp]);
            g2l16(gB[pp] + kt * 32, Bs + ldsoff[pp]);
        }
        __syncthreads();  // staged data visible
        bf16x8 bh[4], bl[4];
#pragma unroll
        for (int ct = 0; ct < 4; ++ct) {
            bh[ct] = *(const bf16x8*)(Bs + boffh[ct]);
            bl[ct] = *(const bf16x8*)(Bs + boffl[ct]);
        }
#pragma unroll
        for (int rt = 0; rt < 8; ++rt) {
            const bf16x8 ah = *(const bf16x8*)(As + aoffh[rt]);
            const bf16x8 al = *(const bf16x8*)(As + aoffl[rt]);
#pragma unroll
            for (int ct = 0; ct < 4; ++ct) {
                acc[rt][ct] = __builtin_amdgcn_mfma_f32_16x16x32_bf16(
                    ah, bh[ct], acc[rt][ct], 0, 0, 0);
                acc[rt][ct] = __builtin_amdgcn_mfma_f32_16x16x32_bf16(
                    ah, bl[ct], acc[rt][ct], 0, 0, 0);
                acc[rt][ct] = __builtin_amdgcn_mfma_f32_16x16x32_bf16(
                    al, bh[ct], acc[rt][ct], 0, 0, 0);
            }
        }
    }
    __syncthreads();  // drain all LDS reads before overlaying As

    if (tid < 256) rnA[tid] = rnormsum(normp, batch * N_ + n0 + tid);

    // ---- row path: rows n (wave's 128-row strip), candidates m (64-col strip)
    float rnm[4];
#pragma unroll
    for (int ct = 0; ct < 4; ++ct)
        rnm[ct] = rnormsum(normp, batch * N_ + m0 + wm + ct * 16 + lm);

#pragma unroll
    for (int rt = 0; rt < 8; ++rt) {
#pragma unroll
        for (int r = 0; r < 4; ++r) {
            const int nrow = n0 + wn + rt * 16 + q * 4 + r;
            float v1 = -3.4e38f, v2 = -3.4e38f;
            int i1 = 0x7fffffff;
#pragma unroll
            for (int ct = 0; ct < 4; ++ct) {
                const int m = m0 + wm + ct * 16 + lm;
                const float v = acc[rt][ct][r] * rnm[ct];
                if (m == nrow) continue;
                if (v > v1) { v2 = v1; v1 = v; i1 = m; }
                else if (v > v2) v2 = v;
            }
#pragma unroll
            for (int d = 1; d < 16; d <<= 1) {
                const float ov1 = __shfl_xor(v1, d, 64);
                const int oi1 = __shfl_xor(i1, d, 64);
                const float ov2 = __shfl_xor(v2, d, 64);
                if (ov1 > v1 || (ov1 == v1 && oi1 < i1)) {
                    v2 = fmaxf(v1, ov2); v1 = ov1; i1 = oi1;
                } else {
                    v2 = fmaxf(v2, ov1);
                }
            }
            if (lm == 0) {
                const int rloc = wn + rt * 16 + q * 4 + r;
                rv1[rloc][w & 3] = v1;
                ri1[rloc][w & 3] = i1;
                rv2[rloc][w & 3] = v2;
            }
        }
    }
    __syncthreads();  // rnA + rv* visible

    // ---- col path: rows m (wave's 64-col strip), candidates n (128-row strip)
    if (!diag) {
#pragma unroll
        for (int ct = 0; ct < 4; ++ct) {
            float v1 = -3.4e38f, v2 = -3.4e38f;
            int i1 = 0x7fffffff;
#pragma unroll
            for (int rt = 0; rt < 8; ++rt) {
#pragma unroll
                for (int r = 0; r < 4; ++r) {
                    const float v = acc[rt][ct][r] * rnA[wn + rt * 16 + q * 4 + r];
                    const int nn = n0 + wn + rt * 16 + q * 4 + r;
                    if (v > v1) { v2 = v1; v1 = v; i1 = nn; }
                    else if (v > v2) v2 = v;
                }
            }
#pragma unroll
            for (int d = 16; d < 64; d <<= 1) {
                const float ov1 = __shfl_xor(v1, d, 64);
                const int oi1 = __shfl_xor(i1, d, 64);
                const float ov2 = __shfl_xor(v2, d, 64);
                if (ov1 > v1 || (ov1 == v1 && oi1 < i1)) {
                    v2 = fmaxf(v1, ov2); v1 = ov1; i1 = oi1;
                } else {
                    v2 = fmaxf(v2, ov1);
                }
            }
            if (q == 0) {
                const int mloc = wm + ct * 16 + lm;
                cv1[mloc][w >> 2] = v1;
                ci1[mloc][w >> 2] = i1;
                cv2[mloc][w >> 2] = v2;
            }
        }
    }
    __syncthreads();

    if (tid < 256) {
        // row result -> slot bm, rows n-strip (merge 4 wm-strip partials)
        {
            float v1 = rv1[tid][0]; int i1 = ri1[tid][0]; float v2 = rv2[tid][0];
#pragma unroll
            for (int s = 1; s < 4; ++s) {
                const float ov1 = rv1[tid][s]; const int oi1 = ri1[tid][s]; const float ov2 = rv2[tid][s];
                if (ov1 > v1 || (ov1 == v1 && oi1 < i1)) { v2 = fmaxf(v1, ov2); v1 = ov1; i1 = oi1; }
                else v2 = fmaxf(v2, ov1);
            }
            const size_t gi = (size_t)(batch * NT2 + bm) * N_ + n0 + tid;
            pval[gi] = v1; pidx[gi] = i1; pval2[gi] = v2;
        }
        // col result -> slot bn, rows m-strip (merge 2 wn-strip partials)
        if (!diag) {
            float v1 = cv1[tid][0]; int i1 = ci1[tid][0]; float v2 = cv2[tid][0];
            const float ov1 = cv1[tid][1]; const int oi1 = ci1[tid][1]; const float ov2 = cv2[tid][1];
            if (ov1 > v1 || (ov1 == v1 && oi1 < i1)) { v2 = fmaxf(v1, ov2); v1 = ov1; i1 = oi1; }
            else v2 = fmaxf(v2, ov1);
            const size_t gi = (size_t)(batch * NT2 + bn) * N_ + m0 + tid;
            pval[gi] = v1; pidx[gi] = i1; pval2[gi] = v2;
        }
    }
}

// -------------------------------------------------------------- combine ----
// 4 threads per row (grid 256x256), each reduces 2 of the 8 tile slots,
// then shfl_xor(1,2) merge. Threshold 4e-5.
__global__ void combine_kernel(const float* __restrict__ pval, const int* __restrict__ pidx,
                               const float* __restrict__ pval2, int* __restrict__ fidx,
                               int* __restrict__ rcnt, int* __restrict__ ridx,
                               unsigned long long* __restrict__ pbest) {
    const int gt = blockIdx.x * 256 + threadIdx.x;  // 65536
    const int row = gt >> 2, part = gt & 3;
    const int batch = row >> 11, n = row & 2047;
    float v1 = -3.4e38f, v2 = -3.4e38f;
    int i1 = 0x7fffffff;
    for (int s = part; s < NT2; s += 4) {
        const size_t gi = (size_t)(batch * NT2 + s) * N_ + n;
        const float ov1 = pval[gi]; const int oi1 = pidx[gi]; const float ov2 = pval2[gi];
        if (ov1 > v1 || (ov1 == v1 && oi1 < i1)) { v2 = fmaxf(v1, ov2); v1 = ov1; i1 = oi1; }
        else v2 = fmaxf(v2, ov1);
    }
#pragma unroll
    for (int d = 1; d < 4; d <<= 1) {
        const float ov1 = __shfl_xor(v1, d, 64);
        const int oi1 = __shfl_xor(i1, d, 64);
        const float ov2 = __shfl_xor(v2, d, 64);
        if (ov1 > v1 || (ov1 == v1 && oi1 < i1)) { v2 = fmaxf(v1, ov2); v1 = ov1; i1 = oi1; }
        else v2 = fmaxf(v2, ov1);
    }
    if (part == 0) {
        fidx[row] = i1;
        if (v1 - v2 < 4e-5f) {
            const int slot = atomicAdd(rcnt, 1);
            ridx[slot] = row;
            pbest[slot] = 0ull;
        }
    }
}

// --------------------------------------------------------------- rescue ----
// (row, 256-m chunk) work items; broadcast xn + coalesced xm; block-reduce;
// one packed-u64 atomicMax per (row, chunk). Grid 2048.
__global__ __launch_bounds__(256) void rescue_kernel(const float* __restrict__ x,
                                                     const float* __restrict__ normp,
                                                     const int* __restrict__ rcnt,
                                                     const int* __restrict__ ridx,
                                                     unsigned long long* __restrict__ pbest) {
    const int cnt = *rcnt;
    const int nwork = cnt << 3;
    const int tid = threadIdx.x;
    __shared__ unsigned long long bk[256];
    for (int wi = blockIdx.x; wi < nwork; wi += gridDim.x) {
        const int rr = wi >> 3, ch = wi & 7;
        const int t = ridx[rr];
        const int batch = t >> 11, n = t & 2047;
        const int m = (ch << 8) + tid;
        const float* xb = x + (size_t)batch * CN_;
        float s0 = 0.f, s1 = 0.f, s2 = 0.f, s3 = 0.f;
        const float* xn = xb + n;
        const float* xm = xb + m;
#pragma unroll 4
        for (int c = 0; c < C_; c += 4) {
            s0 += xn[(size_t)(c + 0) * N_] * xm[(size_t)(c + 0) * N_];
            s1 += xn[(size_t)(c + 1) * N_] * xm[(size_t)(c + 1) * N_];
            s2 += xn[(size_t)(c + 2) * N_] * xm[(size_t)(c + 2) * N_];
            s3 += xn[(size_t)(c + 3) * N_] * xm[(size_t)(c + 3) * N_];
        }
        const float v = ((s0 + s1) + (s2 + s3)) * rnormsum(normp, batch * N_ + m);
        bk[tid] = (m == n) ? 0ull : packkey(v, m);
        __syncthreads();
        for (int sft = 128; sft > 0; sft >>= 1) {
            if (tid < sft) {
                const unsigned long long o = bk[tid + sft];
                if (o > bk[tid]) bk[tid] = o;
            }
            __syncthreads();
        }
        if (tid == 0) atomicMax(&pbest[rr], bk[0]);
        __syncthreads();
    }
}

// ------------------------------- finish: rescue-apply + gate + outputs -----
// r14's measured-best form: grid = 1024 blocks x 512 threads (4 blocks/CU).
// batch = blk&7, 128 ntiles of 16 tokens. Thread (i = t&15, cg = t>>4, 8 c).
// Nontemporal output stores.
__global__ __launch_bounds__(512) void finish_kernel(const float* __restrict__ x,
                                                     const __hip_bfloat16* __restrict__ hiT,
                                                     const __hip_bfloat16* __restrict__ loT,
                                                     const float* __restrict__ W,
                                                     const int* __restrict__ fidx,
                                                     const int* __restrict__ rcnt,
                                                     const int* __restrict__ ridx,
                                                     const unsigned long long* __restrict__ pbest,
                                                     float* __restrict__ out) {
    const int batch = blockIdx.x & 7;
    const int nt = blockIdx.x >> 3;  // 0..127
    const int n0 = nt << 4;
    const int t = threadIdx.x;
    const int i = t & 15, cg = t >> 4;  // cg 0..31, 8 c each

    __shared__ float Wl[1024];
    __shared__ int il[16];
    __shared__ float pl0[32][17], pl1[32][17];
    __shared__ float w0s[16], w1s[16];

    for (int u = t; u < 1024; u += 512) Wl[u] = W[u];
    if (t < 16) il[t] = fidx[batch * N_ + n0 + t];
    __syncthreads();
    {
        const int cnt = *rcnt;
        for (int rr = t; rr < cnt; rr += 512) {
            const int tt = ridx[rr];
            if ((tt >> 11) == batch) {
                const int n = tt & 2047;
                if (n >= n0 && n < n0 + 16) {
                    const unsigned long long k = pbest[rr];
                    il[n - n0] = 2047 - (int)(unsigned)(k & 0xffffffffull);
                }
            }
        }
    }
    __syncthreads();

    const int myrow = il[i];
    const size_t rowb = ((size_t)batch * N_ + myrow) * C_ + cg * 8;

    float fre[8];
    {
        const bf16x8 h = *(const bf16x8*)(hiT + rowb);
        const bf16x8 g = *(const bf16x8*)(loT + rowb);
#pragma unroll
        for (int e = 0; e < 8; ++e) fre[e] = b2f(h[e]) + b2f(g[e]);
    }

    const float* xb = x + (size_t)batch * CN_ + n0 + i;
    float xr[8];
    float l0 = 0.f, l1 = 0.f;
#pragma unroll
    for (int cc = 0; cc < 8; ++cc) {
        const int c = cg * 8 + cc;
        const float xv = xb[(size_t)c * N_];
        xr[cc] = xv;
        l0 += xv * Wl[c] + fre[cc] * Wl[256 + c];
        l1 += xv * Wl[512 + c] + fre[cc] * Wl[768 + c];
    }
    pl0[cg][i] = l0;
    pl1[cg][i] = l1;
    __syncthreads();
    if (t < 16) {
        float L0 = 0.f, L1 = 0.f;
#pragma unroll
        for (int g = 0; g < 32; ++g) { L0 += pl0[g][t]; L1 += pl1[g][t]; }
        const float mx = fmaxf(L0, L1);
        const float e0 = expf(L0 - mx);
        const float e1 = expf(L1 - mx);
        const float inv = 1.0f / (e0 + e1);
        w0s[t] = e0 * inv;
        w1s[t] = e1 * inv;
    }
    __syncthreads();
    const float w0 = w0s[i], w1 = w1s[i];

#pragma unroll
    for (int cc = 0; cc < 8; ++cc) {
        const int c = cg * 8 + cc;
        const size_t off = (size_t)batch * CN_ + (size_t)c * N_ + n0 + i;
        __builtin_nontemporal_store(xr[cc] * w0 + fre[cc] * w1, out + off);
        __builtin_nontemporal_store(fre[cc], out + TOT_ + off);
    }
}

// ---------------------------------------------------------------------------
extern "C" void kernel_launch(void* const* d_in, const int* in_sizes, int n_in,
                              void* d_out, int out_size, void* d_ws, size_t ws_size,
                              hipStream_t stream) {
    const float* x = (const float*)d_in[0];
    const float* W = (const float*)d_in[1];
    float* out = (float*)d_out;

    const size_t BF_BYTES = (size_t)TOT_ * 2;             // 8.39 MB each
    const size_t NORM_BYTES = (size_t)BN_ * 4;            // 64 KB
    const size_t P_BYTES = (size_t)B_ * NT2 * N_ * 4;     // 512 KB each

    uint8_t* p = (uint8_t*)d_ws;
    __hip_bfloat16* hiT = (__hip_bfloat16*)p; p += BF_BYTES;
    __hip_bfloat16* loT = (__hip_bfloat16*)p; p += BF_BYTES;
    float* normp = (float*)p; p += 4 * NORM_BYTES;        // 4 slabs
    float* pval = (float*)p; p += P_BYTES;
    int* pidx = (int*)p; p += P_BYTES;
    float* pval2 = (float*)p; p += P_BYTES;
    int* fidx = (int*)p; p += NORM_BYTES;
    int* rcnt = (int*)p; p += 256;
    int* ridx = (int*)p; p += NORM_BYTES;
    unsigned long long* pbest = (unsigned long long*)p; p += (size_t)BN_ * 8;

    convert_kernel<<<1024, 256, 0, stream>>>(x, hiT, loT, normp, rcnt);
    gram_mfma_kernel<<<B_ * NP2, 512, 0, stream>>>(hiT, loT, normp, pval, pidx, pval2);
    combine_kernel<<<256, 256, 0, stream>>>(pval, pidx, pval2, fidx, rcnt, ridx, pbest);
    rescue_kernel<<<2048, 256, 0, stream>>>(x, normp, rcnt, ridx, pbest);
    finish_kernel<<<1024, 512, 0, stream>>>(x, hiT, loT, W, fidx, rcnt, ridx, pbest, out);
}

// Round 17
// 165.358 us; speedup vs baseline: 1.1639x; 1.1639x over previous
//
#include <hip/hip_runtime.h>
#include <hip/hip_bf16.h>
#include <math.h>

constexpr int B_ = 8;
constexpr int C_ = 256;
constexpr int N_ = 2048;
constexpr int CN_ = C_ * N_;        // 524288
constexpr int TOT_ = B_ * C_ * N_;  // 4194304
constexpr int BN_ = B_ * N_;        // 16384
constexpr int NTILES = 16;          // 128-wide strips
constexpr int NPAIRS = 136;         // triangular tiles per batch
constexpr float EPSC = 256.0f * 1e-6f;

typedef __attribute__((ext_vector_type(8))) short bf16x8;
typedef __attribute__((ext_vector_type(4))) float f32x4;
typedef __attribute__((ext_vector_type(2))) unsigned int u32x2;

__device__ __forceinline__ void g2l16(const void* g, void* l) {
    __builtin_amdgcn_global_load_lds(
        (const __attribute__((address_space(1))) void*)g,
        (__attribute__((address_space(3))) void*)l, 16, 0, 0);
}

__device__ __forceinline__ unsigned short bits(__hip_bfloat16 h) {
    union { __hip_bfloat16 b; unsigned short u; } cv;
    cv.b = h;
    return cv.u;
}

__device__ __forceinline__ float b2f(short s) {
    union { float f; unsigned u; } cv;
    cv.u = ((unsigned)(unsigned short)s) << 16;
    return cv.f;
}

// sortable packed key: (monotone float bits << 32) | (2047 - m)  [lower m wins ties]
__device__ __forceinline__ unsigned long long packkey(float v, int m) {
    const unsigned b = __float_as_uint(v);
    const unsigned u = (b & 0x80000000u) ? ~b : (b | 0x80000000u);
    return ((unsigned long long)u << 32) | (unsigned)(2047 - m);
}

__device__ __forceinline__ unsigned packpair(float a, float b) {
    return ((unsigned)bits(__float2bfloat16(b)) << 16) | bits(__float2bfloat16(a));
}

// norm gather helper: sum the 4 ctile slabs
__device__ __forceinline__ float rnormsum(const float* __restrict__ normp, int idx) {
    return 1.0f / sqrtf(normp[idx] + normp[BN_ + idx] + normp[2 * BN_ + idx] +
                        normp[3 * BN_ + idx] + EPSC);
}

// ----------------------------------------- convert (+ norms) ---------------
// r14 form (measured best): grid = 1024 blocks (batch = blk&7), 256 threads.
// 64c x 64n tile; float4 global loads; red[][] LDS norm reduce.
__global__ __launch_bounds__(256) void convert_kernel(const float* __restrict__ x,
                                                      __hip_bfloat16* __restrict__ hiT,
                                                      __hip_bfloat16* __restrict__ loT,
                                                      float* __restrict__ normp,
                                                      int* __restrict__ rcnt) {
    const int blk = blockIdx.x;
    const int batch = blk & 7;
    const int nt = (blk >> 3) & 31;
    const int ctile = blk >> 8;
    const int n0 = nt << 6, c0 = ctile << 6;
    const int t = threadIdx.x;

    if (blk == 0 && t == 0) rcnt[0] = 0;

    __shared__ float tb[64][65];
    __shared__ float red[16][65];

    // ---- load phase: float4 per thread, 4 passes ----
    const int i4 = t & 15;   // n-quad
    const int j = t >> 4;    // c-row group
    const float* xp = x + (size_t)batch * CN_ + (size_t)c0 * N_ + n0;
#pragma unroll
    for (int p = 0; p < 4; ++p) {
        const int cl = j + p * 16;
        const float4 v = *(const float4*)(xp + (size_t)cl * N_ + 4 * i4);
        tb[cl][4 * i4 + 0] = v.x;
        tb[cl][4 * i4 + 1] = v.y;
        tb[cl][4 * i4 + 2] = v.z;
        tb[cl][4 * i4 + 3] = v.w;
    }
    __syncthreads();

    // ---- pack phase: cq = t&15 (4 c each), nb = t>>4 (16 n per pass) ----
    const int cq = t & 15;
    const int nb = t >> 4;
    const int c = cq << 2;
#pragma unroll
    for (int r = 0; r < 4; ++r) {
        const int n = nb + r * 16;
        const float v0 = tb[c][n], v1 = tb[c + 1][n];
        const float v2 = tb[c + 2][n], v3 = tb[c + 3][n];
        const __hip_bfloat16 h0 = __float2bfloat16(v0);
        const __hip_bfloat16 h1 = __float2bfloat16(v1);
        const __hip_bfloat16 h2 = __float2bfloat16(v2);
        const __hip_bfloat16 h3 = __float2bfloat16(v3);
        const float g0 = v0 - __bfloat162float(h0);
        const float g1 = v1 - __bfloat162float(h1);
        const float g2 = v2 - __bfloat162float(h2);
        const float g3 = v3 - __bfloat162float(h3);
        red[cq][n] = v0 * v0 + v1 * v1 + v2 * v2 + v3 * v3;
        const size_t o = ((size_t)batch * N_ + n0 + n) * C_ + c0 + c;
        u32x2 hp, lp;
        hp[0] = ((unsigned)bits(h1) << 16) | bits(h0);
        hp[1] = ((unsigned)bits(h3) << 16) | bits(h2);
        lp[0] = packpair(g0, g1);
        lp[1] = packpair(g2, g3);
        ((u32x2*)hiT)[o >> 2] = hp;
        ((u32x2*)loT)[o >> 2] = lp;
        __syncthreads();
    }
    if (t < 64) {
        float s = 0.f;
#pragma unroll
        for (int g = 0; g < 16; ++g) s += red[g][t];
        normp[ctile * BN_ + batch * N_ + n0 + t] = s;
    }
}

// ------------------------------- gram (MFMA, triangular) + argmax ----------
// r8/r14 structure (measured 67.2-67.4us, reproducible): 512 threads (8
// waves, wave grid 2x4, 64x32 quadrant each), 128x128 tile, BK=32,
// double-buffered distinct LDS objects, hoisted addresses. Norms from 4
// slabs, rsqrt inline. NEW: s_setprio(1) around the MFMA cluster (T5) --
// 2 independent blocks/CU at uncorrelated phases provide the wave
// role-diversity T5 needs (null only on lockstep grids, m190).
__global__ __launch_bounds__(512) void gram_mfma_kernel(
        const __hip_bfloat16* __restrict__ hiT, const __hip_bfloat16* __restrict__ loT,
        const float* __restrict__ normp,
        float* __restrict__ pval, int* __restrict__ pidx, float* __restrict__ pval2) {
    const int blk = blockIdx.x;
    const int batch = blk & 7;
    int p = blk >> 3;  // 0..135
    int bn = 0;
    while (p >= NTILES - bn) { p -= NTILES - bn; ++bn; }
    const int bm = bn + p;
    const bool diag = (bn == bm);
    const int n0 = bn << 7, m0 = bm << 7;

    __shared__ short As0[128 * 64];
    __shared__ short As1[128 * 64];
    __shared__ short Bs0[128 * 64];
    __shared__ short Bs1[128 * 64];
    short* ov = &As0[0];
    float (*rv1)[4] = (float(*)[4])(ov + 0);
    int (*ri1)[4] = (int(*)[4])(ov + 1024);
    float (*rv2)[4] = (float(*)[4])(ov + 2048);
    float (*cv1)[2] = (float(*)[2])(ov + 3072);
    int (*ci1)[2] = (int(*)[2])(ov + 3584);
    float (*cv2)[2] = (float(*)[2])(ov + 4096);
    float* rnA = (float*)(ov + 4608);

    const int tid = threadIdx.x;
    const int l = tid & 63, w = tid >> 6;
    const int lm = l & 15, q = l >> 4;
    const int x7 = lm & 7;
    const int wn = (w >> 2) << 6;
    const int wm = (w & 3) << 5;

    const size_t bbase = (size_t)batch * CN_;
    const short* gA[2];
    const short* gB[2];
    int ldsoff[2];
#pragma unroll
    for (int pp = 0; pp < 2; ++pp) {
        const int slot = tid + pp * 512;
        const int r = slot >> 3, sidx = slot & 7;
        const int sw = sidx ^ (r & 7);
        const short* base = (const short*)((sw < 4) ? hiT : loT);
        gA[pp] = base + bbase + (size_t)(n0 + r) * C_ + (sw & 3) * 8;
        gB[pp] = base + bbase + (size_t)(m0 + r) * C_ + (sw & 3) * 8;
        ldsoff[pp] = slot * 8;
    }
    int aoff[8], boff[4];
#pragma unroll
    for (int rt = 0; rt < 4; ++rt) {
        const int ra = wn + rt * 16 + lm;
        aoff[rt * 2] = ra * 64 + ((q ^ x7) * 8);
        aoff[rt * 2 + 1] = ra * 64 + (((4 | q) ^ x7) * 8);
    }
#pragma unroll
    for (int ct = 0; ct < 2; ++ct) {
        const int rb = wm + ct * 16 + lm;
        boff[ct * 2] = rb * 64 + ((q ^ x7) * 8);
        boff[ct * 2 + 1] = rb * 64 + (((4 | q) ^ x7) * 8);
    }

    f32x4 acc[4][2];
#pragma unroll
    for (int rt = 0; rt < 4; ++rt)
#pragma unroll
        for (int ct = 0; ct < 2; ++ct) acc[rt][ct] = (f32x4){0.f, 0.f, 0.f, 0.f};

#pragma unroll
    for (int pp = 0; pp < 2; ++pp) {
        g2l16(gA[pp], As0 + ldsoff[pp]);
        g2l16(gB[pp], Bs0 + ldsoff[pp]);
    }
    __syncthreads();

#pragma unroll
    for (int kt = 0; kt < 8; ++kt) {
        short* Ac = (kt & 1) ? As1 : As0;
        short* Bc = (kt & 1) ? Bs1 : Bs0;
        if (kt < 7) {
            short* An = (kt & 1) ? As0 : As1;
            short* Bn = (kt & 1) ? Bs0 : Bs1;
#pragma unroll
            for (int pp = 0; pp < 2; ++pp) {
                g2l16(gA[pp] + (kt + 1) * 32, An + ldsoff[pp]);
                g2l16(gB[pp] + (kt + 1) * 32, Bn + ldsoff[pp]);
            }
        }
        bf16x8 ah[4], al[4], bh[2], bl[2];
#pragma unroll
        for (int rt = 0; rt < 4; ++rt) {
            ah[rt] = *(const bf16x8*)(Ac + aoff[rt * 2]);
            al[rt] = *(const bf16x8*)(Ac + aoff[rt * 2 + 1]);
        }
#pragma unroll
        for (int ct = 0; ct < 2; ++ct) {
            bh[ct] = *(const bf16x8*)(Bc + boff[ct * 2]);
            bl[ct] = *(const bf16x8*)(Bc + boff[ct * 2 + 1]);
        }
        __builtin_amdgcn_s_setprio(1);
#pragma unroll
        for (int rt = 0; rt < 4; ++rt)
#pragma unroll
            for (int ct = 0; ct < 2; ++ct) {
                acc[rt][ct] = __builtin_amdgcn_mfma_f32_16x16x32_bf16(
                    ah[rt], bh[ct], acc[rt][ct], 0, 0, 0);
                acc[rt][ct] = __builtin_amdgcn_mfma_f32_16x16x32_bf16(
                    ah[rt], bl[ct], acc[rt][ct], 0, 0, 0);
                acc[rt][ct] = __builtin_amdgcn_mfma_f32_16x16x32_bf16(
                    al[rt], bh[ct], acc[rt][ct], 0, 0, 0);
            }
        __builtin_amdgcn_s_setprio(0);
        __syncthreads();
    }

    if (tid < 128) rnA[tid] = rnormsum(normp, batch * N_ + n0 + tid);

    float rnm[2];
#pragma unroll
    for (int ct = 0; ct < 2; ++ct)
        rnm[ct] = rnormsum(normp, batch * N_ + m0 + wm + ct * 16 + lm);

#pragma unroll
    for (int rt = 0; rt < 4; ++rt) {
#pragma unroll
        for (int r = 0; r < 4; ++r) {
            const int nrow = n0 + wn + rt * 16 + q * 4 + r;
            float v1 = -3.4e38f, v2 = -3.4e38f;
            int i1 = 0x7fffffff;
#pragma unroll
            for (int ct = 0; ct < 2; ++ct) {
                const int m = m0 + wm + ct * 16 + lm;
                const float v = acc[rt][ct][r] * rnm[ct];
                if (m == nrow) continue;
                if (v > v1) { v2 = v1; v1 = v; i1 = m; }
                else if (v > v2) v2 = v;
            }
#pragma unroll
            for (int d = 1; d < 16; d <<= 1) {
                const float ov1 = __shfl_xor(v1, d, 64);
                const int oi1 = __shfl_xor(i1, d, 64);
                const float ov2 = __shfl_xor(v2, d, 64);
                if (ov1 > v1 || (ov1 == v1 && oi1 < i1)) {
                    v2 = fmaxf(v1, ov2); v1 = ov1; i1 = oi1;
                } else {
                    v2 = fmaxf(v2, ov1);
                }
            }
            if (lm == 0) {
                const int rloc = wn + rt * 16 + q * 4 + r;
                rv1[rloc][w & 3] = v1;
                ri1[rloc][w & 3] = i1;
                rv2[rloc][w & 3] = v2;
            }
        }
    }
    __syncthreads();

    if (!diag) {
        float rnn[4][4];
#pragma unroll
        for (int rt = 0; rt < 4; ++rt)
#pragma unroll
            for (int r = 0; r < 4; ++r) rnn[rt][r] = rnA[wn + rt * 16 + q * 4 + r];
#pragma unroll
        for (int ct = 0; ct < 2; ++ct) {
            float v1 = -3.4e38f, v2 = -3.4e38f;
            int i1 = 0x7fffffff;
#pragma unroll
            for (int rt = 0; rt < 4; ++rt) {
#pragma unroll
                for (int r = 0; r < 4; ++r) {
                    const float v = acc[rt][ct][r] * rnn[rt][r];
                    const int nn = n0 + wn + rt * 16 + q * 4 + r;
                    if (v > v1) { v2 = v1; v1 = v; i1 = nn; }
                    else if (v > v2) v2 = v;
                }
            }
#pragma unroll
            for (int d = 16; d < 64; d <<= 1) {
                const float ov1 = __shfl_xor(v1, d, 64);
                const int oi1 = __shfl_xor(i1, d, 64);
                const float ov2 = __shfl_xor(v2, d, 64);
                if (ov1 > v1 || (ov1 == v1 && oi1 < i1)) {
                    v2 = fmaxf(v1, ov2); v1 = ov1; i1 = oi1;
                } else {
                    v2 = fmaxf(v2, ov1);
                }
            }
            if (q == 0) {
                const int mloc = wm + ct * 16 + lm;
                cv1[mloc][w >> 2] = v1;
                ci1[mloc][w >> 2] = i1;
                cv2[mloc][w >> 2] = v2;
            }
        }
    }
    __syncthreads();

    if (tid < 128) {
        {
            float v1 = rv1[tid][0]; int i1 = ri1[tid][0]; float v2 = rv2[tid][0];
#pragma unroll
            for (int s = 1; s < 4; ++s) {
                const float ov1 = rv1[tid][s]; const int oi1 = ri1[tid][s]; const float ov2 = rv2[tid][s];
                if (ov1 > v1 || (ov1 == v1 && oi1 < i1)) { v2 = fmaxf(v1, ov2); v1 = ov1; i1 = oi1; }
                else v2 = fmaxf(v2, ov1);
            }
            const size_t gi = (size_t)(batch * NTILES + bm) * N_ + n0 + tid;
            pval[gi] = v1; pidx[gi] = i1; pval2[gi] = v2;
        }
        if (!diag) {
            float v1 = cv1[tid][0]; int i1 = ci1[tid][0]; float v2 = cv2[tid][0];
            const float ov1 = cv1[tid][1]; const int oi1 = ci1[tid][1]; const float ov2 = cv2[tid][1];
            if (ov1 > v1 || (ov1 == v1 && oi1 < i1)) { v2 = fmaxf(v1, ov2); v1 = ov1; i1 = oi1; }
            else v2 = fmaxf(v2, ov1);
            const size_t gi = (size_t)(batch * NTILES + bn) * N_ + m0 + tid;
            pval[gi] = v1; pidx[gi] = i1; pval2[gi] = v2;
        }
    }
}

// -------------------------------------------------------------- combine ----
// 4 threads per row (grid 256x256), each reduces 4 of the 16 tile slots,
// then shfl_xor(1,2) merge within the 4-lane group. Threshold 4e-5.
__global__ void combine_kernel(const float* __restrict__ pval, const int* __restrict__ pidx,
                               const float* __restrict__ pval2, int* __restrict__ fidx,
                               int* __restrict__ rcnt, int* __restrict__ ridx,
                               unsigned long long* __restrict__ pbest) {
    const int gt = blockIdx.x * 256 + threadIdx.x;  // 65536
    const int row = gt >> 2, part = gt & 3;
    const int batch = row >> 11, n = row & 2047;
    float v1 = -3.4e38f, v2 = -3.4e38f;
    int i1 = 0x7fffffff;
    for (int s = part; s < NTILES; s += 4) {
        const size_t gi = (size_t)(batch * NTILES + s) * N_ + n;
        const float ov1 = pval[gi]; const int oi1 = pidx[gi]; const float ov2 = pval2[gi];
        if (ov1 > v1 || (ov1 == v1 && oi1 < i1)) { v2 = fmaxf(v1, ov2); v1 = ov1; i1 = oi1; }
        else v2 = fmaxf(v2, ov1);
    }
#pragma unroll
    for (int d = 1; d < 4; d <<= 1) {
        const float ov1 = __shfl_xor(v1, d, 64);
        const int oi1 = __shfl_xor(i1, d, 64);
        const float ov2 = __shfl_xor(v2, d, 64);
        if (ov1 > v1 || (ov1 == v1 && oi1 < i1)) { v2 = fmaxf(v1, ov2); v1 = ov1; i1 = oi1; }
        else v2 = fmaxf(v2, ov1);
    }
    if (part == 0) {
        fidx[row] = i1;
        if (v1 - v2 < 4e-5f) {
            const int slot = atomicAdd(rcnt, 1);
            ridx[slot] = row;
            pbest[slot] = 0ull;
        }
    }
}

// --------------------------------------------------------------- rescue ----
// (row, 256-m chunk) work items; broadcast xn + coalesced xm; block-reduce;
// one packed-u64 atomicMax per (row, chunk). Grid 2048.
__global__ __launch_bounds__(256) void rescue_kernel(const float* __restrict__ x,
                                                     const float* __restrict__ normp,
                                                     const int* __restrict__ rcnt,
                                                     const int* __restrict__ ridx,
                                                     unsigned long long* __restrict__ pbest) {
    const int cnt = *rcnt;
    const int nwork = cnt << 3;
    const int tid = threadIdx.x;
    __shared__ unsigned long long bk[256];
    for (int wi = blockIdx.x; wi < nwork; wi += gridDim.x) {
        const int rr = wi >> 3, ch = wi & 7;
        const int t = ridx[rr];
        const int batch = t >> 11, n = t & 2047;
        const int m = (ch << 8) + tid;
        const float* xb = x + (size_t)batch * CN_;
        float s0 = 0.f, s1 = 0.f, s2 = 0.f, s3 = 0.f;
        const float* xn = xb + n;
        const float* xm = xb + m;
#pragma unroll 4
        for (int c = 0; c < C_; c += 4) {
            s0 += xn[(size_t)(c + 0) * N_] * xm[(size_t)(c + 0) * N_];
            s1 += xn[(size_t)(c + 1) * N_] * xm[(size_t)(c + 1) * N_];
            s2 += xn[(size_t)(c + 2) * N_] * xm[(size_t)(c + 2) * N_];
            s3 += xn[(size_t)(c + 3) * N_] * xm[(size_t)(c + 3) * N_];
        }
        const float v = ((s0 + s1) + (s2 + s3)) * rnormsum(normp, batch * N_ + m);
        bk[tid] = (m == n) ? 0ull : packkey(v, m);
        __syncthreads();
        for (int sft = 128; sft > 0; sft >>= 1) {
            if (tid < sft) {
                const unsigned long long o = bk[tid + sft];
                if (o > bk[tid]) bk[tid] = o;
            }
            __syncthreads();
        }
        if (tid == 0) atomicMax(&pbest[rr], bk[0]);
        __syncthreads();
    }
}

// ------------------------------- finish: rescue-apply + gate + outputs -----
// r14's measured-best form: grid = 1024 blocks x 512 threads (4 blocks/CU).
// batch = blk&7, 128 ntiles of 16 tokens. Thread (i = t&15, cg = t>>4, 8 c).
// Nontemporal output stores.
__global__ __launch_bounds__(512) void finish_kernel(const float* __restrict__ x,
                                                     const __hip_bfloat16* __restrict__ hiT,
                                                     const __hip_bfloat16* __restrict__ loT,
                                                     const float* __restrict__ W,
                                                     const int* __restrict__ fidx,
                                                     const int* __restrict__ rcnt,
                                                     const int* __restrict__ ridx,
                                                     const unsigned long long* __restrict__ pbest,
                                                     float* __restrict__ out) {
    const int batch = blockIdx.x & 7;
    const int nt = blockIdx.x >> 3;  // 0..127
    const int n0 = nt << 4;
    const int t = threadIdx.x;
    const int i = t & 15, cg = t >> 4;  // cg 0..31, 8 c each

    __shared__ float Wl[1024];
    __shared__ int il[16];
    __shared__ float pl0[32][17], pl1[32][17];
    __shared__ float w0s[16], w1s[16];

    for (int u = t; u < 1024; u += 512) Wl[u] = W[u];
    if (t < 16) il[t] = fidx[batch * N_ + n0 + t];
    __syncthreads();
    {
        const int cnt = *rcnt;
        for (int rr = t; rr < cnt; rr += 512) {
            const int tt = ridx[rr];
            if ((tt >> 11) == batch) {
                const int n = tt & 2047;
                if (n >= n0 && n < n0 + 16) {
                    const unsigned long long k = pbest[rr];
                    il[n - n0] = 2047 - (int)(unsigned)(k & 0xffffffffull);
                }
            }
        }
    }
    __syncthreads();

    const int myrow = il[i];
    const size_t rowb = ((size_t)batch * N_ + myrow) * C_ + cg * 8;

    float fre[8];
    {
        const bf16x8 h = *(const bf16x8*)(hiT + rowb);
        const bf16x8 g = *(const bf16x8*)(loT + rowb);
#pragma unroll
        for (int e = 0; e < 8; ++e) fre[e] = b2f(h[e]) + b2f(g[e]);
    }

    const float* xb = x + (size_t)batch * CN_ + n0 + i;
    float xr[8];
    float l0 = 0.f, l1 = 0.f;
#pragma unroll
    for (int cc = 0; cc < 8; ++cc) {
        const int c = cg * 8 + cc;
        const float xv = xb[(size_t)c * N_];
        xr[cc] = xv;
        l0 += xv * Wl[c] + fre[cc] * Wl[256 + c];
        l1 += xv * Wl[512 + c] + fre[cc] * Wl[768 + c];
    }
    pl0[cg][i] = l0;
    pl1[cg][i] = l1;
    __syncthreads();
    if (t < 16) {
        float L0 = 0.f, L1 = 0.f;
#pragma unroll
        for (int g = 0; g < 32; ++g) { L0 += pl0[g][t]; L1 += pl1[g][t]; }
        const float mx = fmaxf(L0, L1);
        const float e0 = expf(L0 - mx);
        const float e1 = expf(L1 - mx);
        const float inv = 1.0f / (e0 + e1);
        w0s[t] = e0 * inv;
        w1s[t] = e1 * inv;
    }
    __syncthreads();
    const float w0 = w0s[i], w1 = w1s[i];

#pragma unroll
    for (int cc = 0; cc < 8; ++cc) {
        const int c = cg * 8 + cc;
        const size_t off = (size_t)batch * CN_ + (size_t)c * N_ + n0 + i;
        __builtin_nontemporal_store(xr[cc] * w0 + fre[cc] * w1, out + off);
        __builtin_nontemporal_store(fre[cc], out + TOT_ + off);
    }
}

// ---------------------------------------------------------------------------
extern "C" void kernel_launch(void* const* d_in, const int* in_sizes, int n_in,
                              void* d_out, int out_size, void* d_ws, size_t ws_size,
                              hipStream_t stream) {
    const float* x = (const float*)d_in[0];
    const float* W = (const float*)d_in[1];
    float* out = (float*)d_out;

    const size_t BF_BYTES = (size_t)TOT_ * 2;             // 8.39 MB each
    const size_t NORM_BYTES = (size_t)BN_ * 4;            // 64 KB
    const size_t P_BYTES = (size_t)B_ * NTILES * N_ * 4;  // 1 MB each

    uint8_t* p = (uint8_t*)d_ws;
    __hip_bfloat16* hiT = (__hip_bfloat16*)p; p += BF_BYTES;
    __hip_bfloat16* loT = (__hip_bfloat16*)p; p += BF_BYTES;
    float* normp = (float*)p; p += 4 * NORM_BYTES;        // 4 slabs
    float* pval = (float*)p; p += P_BYTES;
    int* pidx = (int*)p; p += P_BYTES;
    float* pval2 = (float*)p; p += P_BYTES;
    int* fidx = (int*)p; p += NORM_BYTES;
    int* rcnt = (int*)p; p += 256;
    int* ridx = (int*)p; p += NORM_BYTES;
    unsigned long long* pbest = (unsigned long long*)p; p += (size_t)BN_ * 8;

    convert_kernel<<<1024, 256, 0, stream>>>(x, hiT, loT, normp, rcnt);
    gram_mfma_kernel<<<B_ * NPAIRS, 512, 0, stream>>>(hiT, loT, normp, pval, pidx, pval2);
    combine_kernel<<<256, 256, 0, stream>>>(pval, pidx, pval2, fidx, rcnt, ridx, pbest);
    rescue_kernel<<<2048, 256, 0, stream>>>(x, normp, rcnt, ridx, pbest);
    finish_kernel<<<1024, 512, 0, stream>>>(x, hiT, loT, W, fidx, rcnt, ridx, pbest, out);
}